// Round 12
// baseline (1414.664 us; speedup 1.0000x reference)
//
#include <hip/hip_runtime.h>
#include <math.h>

#define BATCH 8
#define CH 64
#define HW 96
#define HQ 47
#define LQ 2209         // 47*47
#define LP 2304         // padded to 18*128
#define KD 1600         // 64*25
#define NC9 576         // 64*9
#define NTILE 18        // LP/128 l-tiles
#define BK 32           // k-tile in brute (one MFMA K-step)
#define MARGIN 5e-5f    // screen near-tie window (worst-case err ~2.1e-5)
#define MAXCAND 2432    // 72 entries + 18*128 full-tile fallback
#define MAXINL 24       // max candidates resolved inline in finalize

typedef __attribute__((ext_vector_type(8))) short short8;   // 8 bf16 (4 VGPR)
typedef __attribute__((ext_vector_type(4))) float f32x4;    // MFMA C/D frag

// ---------------------------------------------------------------------------
// numpy pairwise sum of squares (blocksize 128, 8 accumulators) — exact
// emulation of numpy's pairwise_sum over a contiguous fp32 axis.
// ---------------------------------------------------------------------------
__device__ float np_pairwise_sq(const float* a, int n) {
#pragma clang fp contract(off)
  if (n <= 128) {
    float r[8];
#pragma unroll
    for (int j = 0; j < 8; ++j) { float x = a[j]; r[j] = x * x; }
    int nm8 = n - (n % 8);
    for (int i = 8; i < nm8; i += 8)
#pragma unroll
      for (int j = 0; j < 8; ++j) { float x = a[i + j]; r[j] = r[j] + x * x; }
    float res = ((r[0] + r[1]) + (r[2] + r[3])) + ((r[4] + r[5]) + (r[6] + r[7]));
    for (int i = nm8; i < n; ++i) { float x = a[i]; res = res + x * x; }
    return res;
  }
  int n2 = n / 2;
  n2 -= n2 % 8;
  float s0 = np_pairwise_sq(a, n2);
  float s1 = np_pairwise_sq(a + n2, n - n2);
  return s0 + s1;
}

// ---------------------------------------------------------------------------
// prep: unfold (k=5,p=1,s=2), L2-normalize with numpy-exact fp32 rounding.
// ---------------------------------------------------------------------------
__global__ __launch_bounds__(256) void prep_np_kernel(
    const float* __restrict__ src, float* __restrict__ out, int mode) {
  __shared__ float sRaw[KD];
  __shared__ float sDen;
  const int pos = blockIdx.x;
  const int b = blockIdx.y;
  const int t = threadIdx.x;
  const size_t obase = ((size_t)b * LP + pos) * KD;

  if (pos >= LQ) {
    for (int k = t; k < KD; k += 256) out[obase + k] = 0.f;
    return;
  }
  const int y0 = (pos / HQ) * 2 - 1, x0 = (pos % HQ) * 2 - 1;
  for (int k = t; k < KD; k += 256) {
    const int c = k / 25, r = k % 25, kh = r / 5, kw = r % 5;
    const int y = y0 + kh, x = x0 + kw;
    float v = 0.f;
    if (y >= 0 && y < HW && x >= 0 && x < HW)
      v = src[(((size_t)b * CH + c) * HW + y) * HW + x];
    sRaw[k] = v;
  }
  __syncthreads();
  if (t == 0) {
    float ss;
    if (mode == 0) {
      ss = np_pairwise_sq(sRaw, KD);
    } else {
#pragma clang fp contract(off)
      float acc = 0.f;
      for (int k2 = 0; k2 < KD; ++k2) {
        float x = sRaw[k2];
        float p = x * x;
        acc = acc + p;
      }
      ss = acc;
    }
    float nrm = (float)sqrt((double)ss);
    sDen = fmaxf(nrm, 1e-12f);
  }
  __syncthreads();
  const float den = sDen;
  for (int k = t; k < KD; k += 256) out[obase + k] = sRaw[k] / den;
}

// ---------------------------------------------------------------------------
// split staging via v_cvt_pk_bf16_f32: hi = cvt_pk(x0,x1);
// lo_i = x_i - bf2f(hi_i); lo = cvt_pk(lo0,lo1).  ~3 VALU/elem.
// ---------------------------------------------------------------------------
__device__ inline void stage8_pk(short* dh, short* dl, int soff,
                                 const float* __restrict__ src) {
  const float4 f0 = *(const float4*)src;
  const float4 f1 = *(const float4*)(src + 4);
  const float x[8] = {f0.x, f0.y, f0.z, f0.w, f1.x, f1.y, f1.z, f1.w};
  int hp[4], lp[4];
#pragma unroll
  for (int p = 0; p < 4; ++p) {
    int h;
    asm("v_cvt_pk_bf16_f32 %0, %1, %2" : "=v"(h) : "v"(x[2 * p]), "v"(x[2 * p + 1]));
    hp[p] = h;
    const float h0 = __uint_as_float(((unsigned)h) << 16);        // src0 -> low16
    const float h1 = __uint_as_float(((unsigned)h) & 0xFFFF0000u);
    const float l0 = x[2 * p] - h0;
    const float l1 = x[2 * p + 1] - h1;
    int l;
    asm("v_cvt_pk_bf16_f32 %0, %1, %2" : "=v"(l) : "v"(l0), "v"(l1));
    lp[p] = l;
  }
  *(int4*)(dh + soff) = *(int4*)hp;   // soff in shorts, 16B-aligned
  *(int4*)(dl + soff) = *(int4*)lp;
}

// compare-exchange: ensure (va,la) >= (vb,lb) in (value desc, index asc) order
__device__ inline void ce(float& va, int& la, float& vb, int& lb) {
  const bool sw = (vb > va) || (vb == va && lb < la);
  const float tv = sw ? vb : va; const float uv = sw ? va : vb;
  const int tl = sw ? lb : la;   const int ul = sw ? la : lb;
  va = tv; la = tl; vb = uv; lb = ul;
}

// merge two desc-sorted 4-lists (a = mine, y = theirs) -> top-4 in a.
// Batcher odd-even merge, pruned to the CEs that affect positions 0..3.
__device__ inline void merge4(float a[4], int al[4], float y[4], int yl[4]) {
  ce(a[0], al[0], y[0], yl[0]);
  ce(a[1], al[1], y[1], yl[1]);
  ce(a[2], al[2], y[2], yl[2]);
  ce(a[3], al[3], y[3], yl[3]);
  ce(a[2], al[2], y[0], yl[0]);
  ce(a[3], al[3], y[1], yl[1]);
  ce(a[1], al[1], a[2], al[2]);
  ce(a[3], al[3], y[0], yl[0]);
}

// ---------------------------------------------------------------------------
// brute_mfma: split-bf16 MFMA screen (hi*hi + hi*lo + lo*hi, fp32 acc).
// LDS layout [g][128][8] with row skew (row+2g)&127. Stores TOP-4 per
// (q, 128-l tile): in-lane top-4 over 16 vals -> shfl butterfly merge
// (m=16,32) -> cross-wave merge via LDS -> global tV4/tL4 (u16 indices).
// ---------------------------------------------------------------------------
__global__ __launch_bounds__(256) void brute_mfma_kernel(
    const float* __restrict__ kn, const float* __restrict__ qn,
    float* __restrict__ tV4, unsigned short* __restrict__ tL4) {
  __shared__ __align__(16) short sKh[4 * 128 * 8];
  __shared__ __align__(16) short sKl[4 * 128 * 8];
  __shared__ __align__(16) short sQh[4 * 128 * 8];
  __shared__ __align__(16) short sQl[4 * 128 * 8];
  __shared__ float sWv[2][128][4];
  __shared__ unsigned short sWl[2][128][4];

  const int t = threadIdx.x;
  const int qt = blockIdx.x, lt = blockIdx.y, b = blockIdx.z;
  const int l0 = lt * 128, q0 = qt * 128;
  const int w = t >> 6, lane = t & 63;
  const int wl = w >> 1, wq = w & 1;
  const int cl = lane & 15, g = lane >> 4;

  f32x4 acc[4][4];
#pragma unroll
  for (int i = 0; i < 4; ++i)
#pragma unroll
    for (int j = 0; j < 4; ++j) {
      f32x4 z = {0.f, 0.f, 0.f, 0.f};
      acc[i][j] = z;
    }

  const int row0 = t >> 2, slot0 = t & 3;
  const int row1 = row0 + 64;
  const int soff0 = slot0 * 1024 + (((row0 + 2 * slot0) & 127) * 8); // shorts
  const int soff1 = slot0 * 1024 + (((row1 + 2 * slot0) & 127) * 8);
  const float* kp0 = kn + ((size_t)(b * LP + l0 + row0)) * KD + slot0 * 8;
  const float* kp1 = kn + ((size_t)(b * LP + l0 + row1)) * KD + slot0 * 8;
  const float* qp0 = qn + ((size_t)(b * LP + q0 + row0)) * KD + slot0 * 8;
  const float* qp1 = qn + ((size_t)(b * LP + q0 + row1)) * KD + slot0 * 8;

  for (int c0 = 0; c0 < KD; c0 += BK) {
    __syncthreads();  // previous iteration's frag reads done
    stage8_pk(sKh, sKl, soff0, kp0); stage8_pk(sKh, sKl, soff1, kp1);
    stage8_pk(sQh, sQl, soff0, qp0); stage8_pk(sQh, sQl, soff1, qp1);
    kp0 += BK; kp1 += BK; qp0 += BK; qp1 += BK;
    __syncthreads();
    short8 Ah[4], Al[4], Bh[4], Bl[4];
#pragma unroll
    for (int i = 0; i < 4; ++i) {
      const int ar = wl * 64 + i * 16 + cl;
      const int sa = g * 1024 + (((ar + 2 * g) & 127) * 8);
      Ah[i] = *(const short8*)(sKh + sa);
      Al[i] = *(const short8*)(sKl + sa);
      const int br = wq * 64 + i * 16 + cl;
      const int sb = g * 1024 + (((br + 2 * g) & 127) * 8);
      Bh[i] = *(const short8*)(sQh + sb);
      Bl[i] = *(const short8*)(sQl + sb);
    }
#pragma unroll
    for (int i = 0; i < 4; ++i)
#pragma unroll
      for (int j = 0; j < 4; ++j) {
        acc[i][j] = __builtin_amdgcn_mfma_f32_16x16x32_bf16(
            Al[i], Bh[j], acc[i][j], 0, 0, 0);
        acc[i][j] = __builtin_amdgcn_mfma_f32_16x16x32_bf16(
            Ah[i], Bl[j], acc[i][j], 0, 0, 0);
        acc[i][j] = __builtin_amdgcn_mfma_f32_16x16x32_bf16(
            Ah[i], Bh[j], acc[i][j], 0, 0, 0);
      }
  }

  // per-wave top-4 over its 64 l's, per q column
#pragma unroll
  for (int j = 0; j < 4; ++j) {
    float v[4] = {-1e30f, -1e30f, -1e30f, -1e30f};
    int li[4] = {0x7fffffff, 0x7fffffff, 0x7fffffff, 0x7fffffff};
#pragma unroll
    for (int i = 0; i < 4; ++i)
#pragma unroll
      for (int r = 0; r < 4; ++r) {
        const int ll = l0 + wl * 64 + i * 16 + g * 4 + r;   // ascending per lane
        const float nv = (ll < LQ) ? acc[i][j][r] : -1e30f;
        if (nv > v[3] || (nv == v[3] && ll < li[3])) {
          v[3] = nv; li[3] = ll;
          ce(v[2], li[2], v[3], li[3]);
          ce(v[1], li[1], v[2], li[2]);
          ce(v[0], li[0], v[1], li[1]);
        }
      }
#pragma unroll
    for (int mm = 0; mm < 2; ++mm) {
      const int m = mm ? 32 : 16;
      float y[4]; int yl[4];
#pragma unroll
      for (int e2 = 0; e2 < 4; ++e2) {
        y[e2] = __shfl_xor(v[e2], m, 64);
        yl[e2] = __shfl_xor(li[e2], m, 64);
      }
      merge4(v, li, y, yl);
    }
    if (lane < 16) {   // g == 0 quarter: all lanes hold identical merged list
      const int qq = wq * 64 + j * 16 + cl;
#pragma unroll
      for (int e2 = 0; e2 < 4; ++e2) {
        sWv[wl][qq][e2] = v[e2];
        sWl[wl][qq][e2] = (unsigned short)(li[e2] > 0xFFFF ? 0xFFFF : li[e2]);
      }
    }
  }
  __syncthreads();
  if (t < 128) {
    float v[4]; int li[4]; float y[4]; int yl[4];
#pragma unroll
    for (int e2 = 0; e2 < 4; ++e2) {
      v[e2] = sWv[0][t][e2]; li[e2] = sWl[0][t][e2];
      y[e2] = sWv[1][t][e2]; yl[e2] = sWl[1][t][e2];
    }
    merge4(v, li, y, yl);
    const int q = q0 + t;
    if (q < LQ) {
      const size_t o = ((size_t)(b * LQ + q) * NTILE + lt) * 4;
#pragma unroll
      for (int e2 = 0; e2 < 4; ++e2) {
        tV4[o + e2] = v[e2];
        tL4[o + e2] = (unsigned short)(li[e2] > 0xFFFF ? 0xFFFF : li[e2]);
      }
    }
  }
}

// ---------------------------------------------------------------------------
// finalize_exact: per-query thread. Screen top-1 over 72 entries; if the
// candidate set {entries >= v1-MARGIN} is a singleton -> screen decides.
// Else resolve INLINE: exact fp64 dot per candidate (4-acc fixed order,
// error ~1e-13 << fp32 ulp), fp32-round, argmax with first-index ties.
// Only if a tile's 4th-best clears the threshold (hidden candidates) or
// nc > MAXINL does the query go to the (statistically empty) fallback.
// ---------------------------------------------------------------------------
__global__ __launch_bounds__(256) void finalize_exact_kernel(
    const float* __restrict__ tV4, const unsigned short* __restrict__ tL4,
    const float* __restrict__ kn, const float* __restrict__ qn,
    float* __restrict__ S, int* __restrict__ final_l,
    int* __restrict__ fb_list, int* __restrict__ fb_cnt) {
  const int q = blockIdx.x * 256 + threadIdx.x;
  const int b = blockIdx.z;
  if (q >= LQ) return;
  const size_t cb = (size_t)(b * LQ + q) * NTILE * 4;

  float v1 = -1e30f; int l1 = 0x7fffffff;
  for (int i = 0; i < NTILE * 4; ++i) {
    const float v = tV4[cb + i];
    const int l = tL4[cb + i];
    if (v > v1 || (v == v1 && l < l1)) { v1 = v; l1 = l; }
  }
  const float thr = v1 - MARGIN;

  int nc = 0;
  bool fb = false;
  for (int i = 0; i < NTILE * 4; ++i) {
    if (tV4[cb + i] >= thr) ++nc;
    if ((i & 3) == 3 && tV4[cb + i] >= thr) fb = true;  // tile 4th-best clears
  }
  if (nc > MAXINL) fb = true;

  if (fb) {
    S[b * LQ + q] = v1;                    // provisional (screen v1 -> thr basis)
    final_l[b * LQ + q] = l1;
    const int slot = atomicAdd(fb_cnt, 1);
    if (slot < BATCH * LQ) fb_list[slot] = b * LQ + q;
    return;
  }
  if (nc <= 1) {                            // screen gap >= MARGIN: decided
    S[b * LQ + q] = v1;
    final_l[b * LQ + q] = l1;
    return;
  }
  // inline exact resolution over the candidate set
  const float* qr = qn + ((size_t)(b * LP + q)) * KD;
  float bf = -1e30f; int bl = 0x7fffffff;
  for (int i = 0; i < NTILE * 4; ++i) {
    const float v = tV4[cb + i];
    if (v < thr) continue;
    const int l = tL4[cb + i];
    const float* kr = kn + ((size_t)(b * LP + l)) * KD;
    double a0 = 0, a1 = 0, a2 = 0, a3 = 0;
    for (int c = 0; c < KD; c += 4) {
      a0 = fma((double)kr[c], (double)qr[c], a0);
      a1 = fma((double)kr[c + 1], (double)qr[c + 1], a1);
      a2 = fma((double)kr[c + 2], (double)qr[c + 2], a2);
      a3 = fma((double)kr[c + 3], (double)qr[c + 3], a3);
    }
    const float f = (float)((a0 + a1) + (a2 + a3));  // fp32-rounded exact dot
    if (f > bf || (f == bf && l < bl)) { bf = f; bl = l; }
  }
  S[b * LQ + q] = bf;
  final_l[b * LQ + q] = bl;
}

// ---------------------------------------------------------------------------
// fallback refine (statistically never runs): one block per fallback query.
// Candidates = stored entries >= S[bq]-MARGIN plus full 128-l ranges of any
// tile whose 4th-best clears the threshold. Exact fp64 dot per candidate
// (one wave each), fp32-round, argmax first-index. Writes S/final_l.
// ---------------------------------------------------------------------------
__global__ __launch_bounds__(256) void refine_kernel(
    const int* __restrict__ fb_list, const int* __restrict__ fb_cnt,
    const float* __restrict__ kn, const float* __restrict__ qn,
    const float* __restrict__ tV4, const unsigned short* __restrict__ tL4,
    float* __restrict__ S, int* __restrict__ final_l) {
  __shared__ float sQrow[KD];
  __shared__ int sList[MAXCAND];
  __shared__ int sCnt;
  __shared__ float sBv[4];
  __shared__ int sBl[4];
  int n = *fb_cnt;
  if (n <= 0) return;
  if (n > BATCH * LQ) n = BATCH * LQ;
  const int t = threadIdx.x;
  const int wid = t >> 6, lane = t & 63;
  for (int e = blockIdx.x; e < n; e += gridDim.x) {
    __syncthreads();  // protect previous iteration's LDS reads
    const int bq = fb_list[e];
    const int b = bq / LQ, q = bq % LQ;
    if (t == 0) sCnt = 0;
    for (int k = t; k < KD; k += 256)
      sQrow[k] = qn[((size_t)(b * LP + q)) * KD + k];
    __syncthreads();
    const float thr = S[bq] - MARGIN;     // S holds screen v1 for fb queries
    const size_t cb = (size_t)(b * LQ + q) * NTILE * 4;
    if (t < NTILE * 4) {
      const float v = tV4[cb + t];
      if (v >= thr) {
        const int l = tL4[cb + t];
        if (l < LQ) { const int p = atomicAdd(&sCnt, 1); sList[p] = l; }
      }
    }
    if (t < NTILE) {
      const float v3 = tV4[cb + t * 4 + 3];   // tile's 4th-best
      if (v3 >= thr) {                         // tile may hide candidates
        const int lbase = t * 128;
        const int p = atomicAdd(&sCnt, 128);
        for (int m2 = 0; m2 < 128; ++m2) {
          const int ll = lbase + m2;
          sList[p + m2] = (ll < LQ) ? ll : 0;  // extra valid l's are harmless
        }
      }
    }
    __syncthreads();
    const int nc = sCnt;
    float bf = -1e30f; int bl = 0x7fffffff;
    for (int c = wid; c < nc; c += 4) {
      const int l = sList[c];
      const float* kr = kn + ((size_t)(b * LP + l)) * KD;
      double acc = 0.0;
#pragma unroll
      for (int k = 0; k < 25; ++k)
        acc = fma((double)kr[lane + 64 * k], (double)sQrow[lane + 64 * k], acc);
#pragma unroll
      for (int m2 = 1; m2 < 64; m2 <<= 1) acc += __shfl_xor(acc, m2, 64);
      const float f = (float)acc;              // fp32-rounded exact dot
      if (f > bf || (f == bf && l < bl)) { bf = f; bl = l; }
    }
    if (lane == 0) { sBv[wid] = bf; sBl[wid] = bl; }
    __syncthreads();
    if (t == 0) {
      float v1 = sBv[0]; int l1 = sBl[0];
#pragma unroll
      for (int wv = 1; wv < 4; ++wv)
        if (sBv[wv] > v1 || (sBv[wv] == v1 && sBl[wv] < l1)) {
          v1 = sBv[wv]; l1 = sBl[wv];
        }
      S[bq] = v1; final_l[bq] = l1;
    }
  }
}

// ---------------------------------------------------------------------------
// gather: value patches (k=3,p=1,s=1) at argmax positions.
// ---------------------------------------------------------------------------
__global__ __launch_bounds__(256) void gather_kernel(
    const int* __restrict__ final_l, const float* __restrict__ value,
    float* __restrict__ T) {
  const int q = blockIdx.x * 256 + threadIdx.x;
  const int g = blockIdx.y;
  const int b = blockIdx.z;
  if (q >= LQ) return;
  const int l = final_l[b * LQ + q];
  const int y0 = l / HW - 1;
  const int x0 = l % HW - 1;
#pragma unroll
  for (int cc = 0; cc < 36; ++cc) {
    const int c9 = g * 36 + cc;
    const int c = c9 / 9, r = c9 % 9;
    const int kh = r / 3, kw = r % 3;
    const int y = y0 + kh, x = x0 + kw;
    float v = 0.f;
    if (y >= 0 && y < HW && x >= 0 && x < HW)
      v = value[(((size_t)b * CH + c) * HW + y) * HW + x];
    T[((size_t)(b * NC9 + c9)) * LQ + q] = v;
  }
}

// ---------------------------------------------------------------------------
extern "C" void kernel_launch(void* const* d_in, const int* in_sizes, int n_in,
                              void* d_out, int out_size, void* d_ws,
                              size_t ws_size, hipStream_t stream) {
  const float* queue = (const float*)d_in[0];
  const float* key   = (const float*)d_in[1];
  const float* value = (const float*)d_in[2];
  float* S = (float*)d_out;
  float* T = S + (size_t)BATCH * LQ;

  char* ws = (char*)d_ws;
  const size_t arr = (size_t)BATCH * LP * KD * sizeof(float);  // 117,964,800 B
  float* kn = (float*)(ws);
  float* qn = (float*)(ws + arr);
  size_t off = 2 * arr;
  const size_t nc4 = (size_t)BATCH * LQ * NTILE * 4;   // 1,272,384 entries
  float* tV4 = (float*)(ws + off); off += nc4 * 4;
  unsigned short* tL4 = (unsigned short*)(ws + off); off += nc4 * 2;
  int* final_l = (int*)(ws + off); off += (size_t)BATCH * LQ * 4;
  int* fb_list = (int*)(ws + off); off += (size_t)BATCH * LQ * 4;
  off = (off + 255) & ~(size_t)255;
  int* fb_cnt = (int*)(ws + off);

  hipMemsetAsync(fb_cnt, 0, sizeof(int), stream);
  prep_np_kernel<<<dim3(LP, BATCH), 256, 0, stream>>>(key, kn, 0);
  prep_np_kernel<<<dim3(LP, BATCH), 256, 0, stream>>>(queue, qn, 1);
  brute_mfma_kernel<<<dim3(LP / 128, LP / 128, BATCH), 256, 0, stream>>>(
      kn, qn, tV4, tL4);
  finalize_exact_kernel<<<dim3((LQ + 255) / 256, 1, BATCH), 256, 0, stream>>>(
      tV4, tL4, kn, qn, S, final_l, fb_list, fb_cnt);
  refine_kernel<<<dim3(512), 256, 0, stream>>>(
      fb_list, fb_cnt, kn, qn, tV4, tL4, S, final_l);
  gather_kernel<<<dim3((LQ + 255) / 256, 16, BATCH), 256, 0, stream>>>(
      final_l, value, T);
}

// Round 13
// 1297.288 us; speedup vs baseline: 1.0905x; 1.0905x over previous
//
#include <hip/hip_runtime.h>
#include <math.h>

#define BATCH 8
#define CH 64
#define HW 96
#define HQ 47
#define LQ 2209         // 47*47
#define LP 2304         // padded to 18*128
#define KD 1600         // 64*25
#define NC9 576         // 64*9
#define NTILE 18        // LP/128 l-tiles
#define BK 32           // k-tile in brute (one MFMA K-step)
#define MARGIN 5e-5f    // screen near-tie window (worst-case err ~2.1e-5)
#define MAXCAND 2432    // 72 entries + 18*128 full-tile fallback

typedef __attribute__((ext_vector_type(8))) short short8;   // 8 bf16 (4 VGPR)
typedef __attribute__((ext_vector_type(4))) float f32x4;    // MFMA C/D frag

// ---------------------------------------------------------------------------
// numpy pairwise sum of squares (blocksize 128, 8 accumulators) — exact
// emulation of numpy's pairwise_sum over a contiguous fp32 axis.
// ---------------------------------------------------------------------------
__device__ float np_pairwise_sq(const float* a, int n) {
#pragma clang fp contract(off)
  if (n <= 128) {
    float r[8];
#pragma unroll
    for (int j = 0; j < 8; ++j) { float x = a[j]; r[j] = x * x; }
    int nm8 = n - (n % 8);
    for (int i = 8; i < nm8; i += 8)
#pragma unroll
      for (int j = 0; j < 8; ++j) { float x = a[i + j]; r[j] = r[j] + x * x; }
    float res = ((r[0] + r[1]) + (r[2] + r[3])) + ((r[4] + r[5]) + (r[6] + r[7]));
    for (int i = nm8; i < n; ++i) { float x = a[i]; res = res + x * x; }
    return res;
  }
  int n2 = n / 2;
  n2 -= n2 % 8;
  float s0 = np_pairwise_sq(a, n2);
  float s1 = np_pairwise_sq(a + n2, n - n2);
  return s0 + s1;
}

// ---------------------------------------------------------------------------
// prep: unfold (k=5,p=1,s=2), L2-normalize with numpy-exact fp32 rounding.
// ---------------------------------------------------------------------------
__global__ __launch_bounds__(256) void prep_np_kernel(
    const float* __restrict__ src, float* __restrict__ out, int mode) {
  __shared__ float sRaw[KD];
  __shared__ float sDen;
  const int pos = blockIdx.x;
  const int b = blockIdx.y;
  const int t = threadIdx.x;
  const size_t obase = ((size_t)b * LP + pos) * KD;

  if (pos >= LQ) {
    for (int k = t; k < KD; k += 256) out[obase + k] = 0.f;
    return;
  }
  const int y0 = (pos / HQ) * 2 - 1, x0 = (pos % HQ) * 2 - 1;
  for (int k = t; k < KD; k += 256) {
    const int c = k / 25, r = k % 25, kh = r / 5, kw = r % 5;
    const int y = y0 + kh, x = x0 + kw;
    float v = 0.f;
    if (y >= 0 && y < HW && x >= 0 && x < HW)
      v = src[(((size_t)b * CH + c) * HW + y) * HW + x];
    sRaw[k] = v;
  }
  __syncthreads();
  if (t == 0) {
    float ss;
    if (mode == 0) {
      ss = np_pairwise_sq(sRaw, KD);
    } else {
#pragma clang fp contract(off)
      float acc = 0.f;
      for (int k2 = 0; k2 < KD; ++k2) {
        float x = sRaw[k2];
        float p = x * x;
        acc = acc + p;
      }
      ss = acc;
    }
    float nrm = (float)sqrt((double)ss);
    sDen = fmaxf(nrm, 1e-12f);
  }
  __syncthreads();
  const float den = sDen;
  for (int k = t; k < KD; k += 256) out[obase + k] = sRaw[k] / den;
}

// ---------------------------------------------------------------------------
// split staging via v_cvt_pk_bf16_f32: hi = cvt_pk(x0,x1);
// lo_i = x_i - bf2f(hi_i); lo = cvt_pk(lo0,lo1).  ~3 VALU/elem.
// ---------------------------------------------------------------------------
__device__ inline void stage8_pk(short* dh, short* dl, int soff,
                                 const float* __restrict__ src) {
  const float4 f0 = *(const float4*)src;
  const float4 f1 = *(const float4*)(src + 4);
  const float x[8] = {f0.x, f0.y, f0.z, f0.w, f1.x, f1.y, f1.z, f1.w};
  int hp[4], lp[4];
#pragma unroll
  for (int p = 0; p < 4; ++p) {
    int h;
    asm("v_cvt_pk_bf16_f32 %0, %1, %2" : "=v"(h) : "v"(x[2 * p]), "v"(x[2 * p + 1]));
    hp[p] = h;
    const float h0 = __uint_as_float(((unsigned)h) << 16);        // src0 -> low16
    const float h1 = __uint_as_float(((unsigned)h) & 0xFFFF0000u);
    const float l0 = x[2 * p] - h0;
    const float l1 = x[2 * p + 1] - h1;
    int l;
    asm("v_cvt_pk_bf16_f32 %0, %1, %2" : "=v"(l) : "v"(l0), "v"(l1));
    lp[p] = l;
  }
  *(int4*)(dh + soff) = *(int4*)hp;   // soff in shorts, 16B-aligned
  *(int4*)(dl + soff) = *(int4*)lp;
}

// compare-exchange: ensure (va,la) >= (vb,lb) in (value desc, index asc) order
__device__ inline void ce(float& va, int& la, float& vb, int& lb) {
  const bool sw = (vb > va) || (vb == va && lb < la);
  const float tv = sw ? vb : va; const float uv = sw ? va : vb;
  const int tl = sw ? lb : la;   const int ul = sw ? la : lb;
  va = tv; la = tl; vb = uv; lb = ul;
}

// merge two desc-sorted 4-lists (a = mine, y = theirs) -> top-4 in a.
// Batcher odd-even merge, pruned to the CEs that affect positions 0..3.
__device__ inline void merge4(float a[4], int al[4], float y[4], int yl[4]) {
  ce(a[0], al[0], y[0], yl[0]);
  ce(a[1], al[1], y[1], yl[1]);
  ce(a[2], al[2], y[2], yl[2]);
  ce(a[3], al[3], y[3], yl[3]);
  ce(a[2], al[2], y[0], yl[0]);
  ce(a[3], al[3], y[1], yl[1]);
  ce(a[1], al[1], a[2], al[2]);
  ce(a[3], al[3], y[0], yl[0]);
}

// ---------------------------------------------------------------------------
// brute_mfma: split-bf16 MFMA screen (hi*hi + hi*lo + lo*hi, fp32 acc).
// LDS layout [g][128][8] with row skew (row+2g)&127. Stores TOP-4 per
// (q, 128-l tile). DIAGNOSTIC: launched as two z-halves (zbase 0 and 4)
// so each dispatch is ~325 us and any ~>330 us "ghost" kernel surfaces
// in the top-5 profile by name. Per-block work is independent per b, so
// the split is bit-identical.
// ---------------------------------------------------------------------------
__global__ __launch_bounds__(256) void brute_mfma_kernel(
    const float* __restrict__ kn, const float* __restrict__ qn,
    float* __restrict__ tV4, unsigned short* __restrict__ tL4, int zbase) {
  __shared__ __align__(16) short sKh[4 * 128 * 8];
  __shared__ __align__(16) short sKl[4 * 128 * 8];
  __shared__ __align__(16) short sQh[4 * 128 * 8];
  __shared__ __align__(16) short sQl[4 * 128 * 8];
  __shared__ float sWv[2][128][4];
  __shared__ unsigned short sWl[2][128][4];

  const int t = threadIdx.x;
  const int qt = blockIdx.x, lt = blockIdx.y, b = blockIdx.z + zbase;
  const int l0 = lt * 128, q0 = qt * 128;
  const int w = t >> 6, lane = t & 63;
  const int wl = w >> 1, wq = w & 1;
  const int cl = lane & 15, g = lane >> 4;

  f32x4 acc[4][4];
#pragma unroll
  for (int i = 0; i < 4; ++i)
#pragma unroll
    for (int j = 0; j < 4; ++j) {
      f32x4 z = {0.f, 0.f, 0.f, 0.f};
      acc[i][j] = z;
    }

  const int row0 = t >> 2, slot0 = t & 3;
  const int row1 = row0 + 64;
  const int soff0 = slot0 * 1024 + (((row0 + 2 * slot0) & 127) * 8); // shorts
  const int soff1 = slot0 * 1024 + (((row1 + 2 * slot0) & 127) * 8);
  const float* kp0 = kn + ((size_t)(b * LP + l0 + row0)) * KD + slot0 * 8;
  const float* kp1 = kn + ((size_t)(b * LP + l0 + row1)) * KD + slot0 * 8;
  const float* qp0 = qn + ((size_t)(b * LP + q0 + row0)) * KD + slot0 * 8;
  const float* qp1 = qn + ((size_t)(b * LP + q0 + row1)) * KD + slot0 * 8;

  for (int c0 = 0; c0 < KD; c0 += BK) {
    __syncthreads();  // previous iteration's frag reads done
    stage8_pk(sKh, sKl, soff0, kp0); stage8_pk(sKh, sKl, soff1, kp1);
    stage8_pk(sQh, sQl, soff0, qp0); stage8_pk(sQh, sQl, soff1, qp1);
    kp0 += BK; kp1 += BK; qp0 += BK; qp1 += BK;
    __syncthreads();
    short8 Ah[4], Al[4], Bh[4], Bl[4];
#pragma unroll
    for (int i = 0; i < 4; ++i) {
      const int ar = wl * 64 + i * 16 + cl;
      const int sa = g * 1024 + (((ar + 2 * g) & 127) * 8);
      Ah[i] = *(const short8*)(sKh + sa);
      Al[i] = *(const short8*)(sKl + sa);
      const int br = wq * 64 + i * 16 + cl;
      const int sb = g * 1024 + (((br + 2 * g) & 127) * 8);
      Bh[i] = *(const short8*)(sQh + sb);
      Bl[i] = *(const short8*)(sQl + sb);
    }
#pragma unroll
    for (int i = 0; i < 4; ++i)
#pragma unroll
      for (int j = 0; j < 4; ++j) {
        acc[i][j] = __builtin_amdgcn_mfma_f32_16x16x32_bf16(
            Al[i], Bh[j], acc[i][j], 0, 0, 0);
        acc[i][j] = __builtin_amdgcn_mfma_f32_16x16x32_bf16(
            Ah[i], Bl[j], acc[i][j], 0, 0, 0);
        acc[i][j] = __builtin_amdgcn_mfma_f32_16x16x32_bf16(
            Ah[i], Bh[j], acc[i][j], 0, 0, 0);
      }
  }

  // per-wave top-4 over its 64 l's, per q column
#pragma unroll
  for (int j = 0; j < 4; ++j) {
    float v[4] = {-1e30f, -1e30f, -1e30f, -1e30f};
    int li[4] = {0x7fffffff, 0x7fffffff, 0x7fffffff, 0x7fffffff};
#pragma unroll
    for (int i = 0; i < 4; ++i)
#pragma unroll
      for (int r = 0; r < 4; ++r) {
        const int ll = l0 + wl * 64 + i * 16 + g * 4 + r;   // ascending per lane
        const float nv = (ll < LQ) ? acc[i][j][r] : -1e30f;
        if (nv > v[3] || (nv == v[3] && ll < li[3])) {
          v[3] = nv; li[3] = ll;
          ce(v[2], li[2], v[3], li[3]);
          ce(v[1], li[1], v[2], li[2]);
          ce(v[0], li[0], v[1], li[1]);
        }
      }
#pragma unroll
    for (int mm = 0; mm < 2; ++mm) {
      const int m = mm ? 32 : 16;
      float y[4]; int yl[4];
#pragma unroll
      for (int e2 = 0; e2 < 4; ++e2) {
        y[e2] = __shfl_xor(v[e2], m, 64);
        yl[e2] = __shfl_xor(li[e2], m, 64);
      }
      merge4(v, li, y, yl);
    }
    if (lane < 16) {   // g == 0 quarter: all lanes hold identical merged list
      const int qq = wq * 64 + j * 16 + cl;
#pragma unroll
      for (int e2 = 0; e2 < 4; ++e2) {
        sWv[wl][qq][e2] = v[e2];
        sWl[wl][qq][e2] = (unsigned short)(li[e2] > 0xFFFF ? 0xFFFF : li[e2]);
      }
    }
  }
  __syncthreads();
  if (t < 128) {
    float v[4]; int li[4]; float y[4]; int yl[4];
#pragma unroll
    for (int e2 = 0; e2 < 4; ++e2) {
      v[e2] = sWv[0][t][e2]; li[e2] = sWl[0][t][e2];
      y[e2] = sWv[1][t][e2]; yl[e2] = sWl[1][t][e2];
    }
    merge4(v, li, y, yl);
    const int q = q0 + t;
    if (q < LQ) {
      const size_t o = ((size_t)(b * LQ + q) * NTILE + lt) * 4;
#pragma unroll
      for (int e2 = 0; e2 < 4; ++e2) {
        tV4[o + e2] = v[e2];
        tL4[o + e2] = (unsigned short)(li[e2] > 0xFFFF ? 0xFFFF : li[e2]);
      }
    }
  }
}

// ---------------------------------------------------------------------------
// finalize: scan 18 tiles x top-4 -> screen top-2 (value desc, index asc).
// Gap >= MARGIN guarantees screen argmax == reference fp32-rounded argmax;
// otherwise flag into a flat list for candidate-based exact refinement.
// ---------------------------------------------------------------------------
__global__ __launch_bounds__(256) void finalize32_kernel(
    const float* __restrict__ tV4, const unsigned short* __restrict__ tL4,
    float* __restrict__ S, int* __restrict__ final_l,
    int* __restrict__ flag_list, int* __restrict__ flag_cnt) {
  const int q = blockIdx.x * 256 + threadIdx.x;
  const int b = blockIdx.z;
  if (q >= LQ) return;
  const size_t cb = (size_t)(b * LQ + q) * NTILE * 4;
  float v1 = -1e30f, v2 = -1e30f;
  int l1 = 0x7fffffff, l2 = 0x7fffffff;
  for (int i = 0; i < NTILE * 4; ++i) {
    const float v = tV4[cb + i];
    const int l = tL4[cb + i];
    if (v > v1 || (v == v1 && l < l1)) { v2 = v1; l2 = l1; v1 = v; l1 = l; }
    else if (v > v2 || (v == v2 && l < l2)) { v2 = v; l2 = l; }
  }
  S[b * LQ + q] = v1;
  final_l[b * LQ + q] = l1;
  if (v1 - v2 < MARGIN) {
    const int slot = atomicAdd(flag_cnt, 1);
    if (slot < BATCH * LQ) flag_list[slot] = b * LQ + q;
  }
}

// ---------------------------------------------------------------------------
// refine: one block per flagged query (grid-stride). Candidates = stored
// tile entries with screen value >= v1 - MARGIN; if a tile's 4th entry
// clears the threshold the tile may hide more -> add its whole 128-l range
// (keeps the guarantee unconditional). Exact fp64 dot per candidate (one
// wave each: 25 lane-strided FMAs + xor-butterfly reduce, deterministic),
// fp32-round, argmax with first-index tie rule. Writes S/final_l directly.
// ---------------------------------------------------------------------------
__global__ __launch_bounds__(256) void refine_kernel(
    const int* __restrict__ flag_list, const int* __restrict__ flag_cnt,
    const float* __restrict__ kn, const float* __restrict__ qn,
    const float* __restrict__ tV4, const unsigned short* __restrict__ tL4,
    float* __restrict__ S, int* __restrict__ final_l) {
  __shared__ float sQrow[KD];
  __shared__ int sList[MAXCAND];
  __shared__ int sCnt;
  __shared__ float sBv[4];
  __shared__ int sBl[4];
  int n = *flag_cnt;
  if (n <= 0) return;
  if (n > BATCH * LQ) n = BATCH * LQ;
  const int t = threadIdx.x;
  const int wid = t >> 6, lane = t & 63;
  for (int e = blockIdx.x; e < n; e += gridDim.x) {
    __syncthreads();  // protect previous iteration's LDS reads
    const int bq = flag_list[e];
    const int b = bq / LQ, q = bq % LQ;
    if (t == 0) sCnt = 0;
    for (int k = t; k < KD; k += 256)
      sQrow[k] = qn[((size_t)(b * LP + q)) * KD + k];
    __syncthreads();
    const float thr = S[bq] - MARGIN;     // S holds screen v1 here
    const size_t cb = (size_t)(b * LQ + q) * NTILE * 4;
    if (t < NTILE * 4) {
      const float v = tV4[cb + t];
      if (v >= thr) {
        const int l = tL4[cb + t];
        if (l < LQ) { const int p = atomicAdd(&sCnt, 1); sList[p] = l; }
      }
    }
    if (t < NTILE) {
      const float v3 = tV4[cb + t * 4 + 3];   // tile's 4th-best
      if (v3 >= thr) {                         // tile may hide candidates
        const int lbase = t * 128;
        const int p = atomicAdd(&sCnt, 128);
        for (int m2 = 0; m2 < 128; ++m2) {
          const int ll = lbase + m2;
          sList[p + m2] = (ll < LQ) ? ll : 0;  // extra valid l's are harmless
        }
      }
    }
    __syncthreads();
    const int nc = sCnt;
    float bf = -1e30f; int bl = 0x7fffffff;
    for (int c = wid; c < nc; c += 4) {
      const int l = sList[c];
      const float* kr = kn + ((size_t)(b * LP + l)) * KD;
      double acc = 0.0;
#pragma unroll
      for (int k = 0; k < 25; ++k)
        acc = fma((double)kr[lane + 64 * k], (double)sQrow[lane + 64 * k], acc);
#pragma unroll
      for (int m2 = 1; m2 < 64; m2 <<= 1) acc += __shfl_xor(acc, m2, 64);
      const float f = (float)acc;              // fp32-rounded exact dot
      if (f > bf || (f == bf && l < bl)) { bf = f; bl = l; }
    }
    if (lane == 0) { sBv[wid] = bf; sBl[wid] = bl; }
    __syncthreads();
    if (t == 0) {
      float v1 = sBv[0]; int l1 = sBl[0];
#pragma unroll
      for (int wv = 1; wv < 4; ++wv)
        if (sBv[wv] > v1 || (sBv[wv] == v1 && sBl[wv] < l1)) {
          v1 = sBv[wv]; l1 = sBl[wv];
        }
      S[bq] = v1; final_l[bq] = l1;
    }
  }
}

// ---------------------------------------------------------------------------
// gather: value patches (k=3,p=1,s=1) at argmax positions.
// ---------------------------------------------------------------------------
__global__ __launch_bounds__(256) void gather_kernel(
    const int* __restrict__ final_l, const float* __restrict__ value,
    float* __restrict__ T) {
  const int q = blockIdx.x * 256 + threadIdx.x;
  const int g = blockIdx.y;
  const int b = blockIdx.z;
  if (q >= LQ) return;
  const int l = final_l[b * LQ + q];
  const int y0 = l / HW - 1;
  const int x0 = l % HW - 1;
#pragma unroll
  for (int cc = 0; cc < 36; ++cc) {
    const int c9 = g * 36 + cc;
    const int c = c9 / 9, r = c9 % 9;
    const int kh = r / 3, kw = r % 3;
    const int y = y0 + kh, x = x0 + kw;
    float v = 0.f;
    if (y >= 0 && y < HW && x >= 0 && x < HW)
      v = value[(((size_t)b * CH + c) * HW + y) * HW + x];
    T[((size_t)(b * NC9 + c9)) * LQ + q] = v;
  }
}

// ---------------------------------------------------------------------------
extern "C" void kernel_launch(void* const* d_in, const int* in_sizes, int n_in,
                              void* d_out, int out_size, void* d_ws,
                              size_t ws_size, hipStream_t stream) {
  const float* queue = (const float*)d_in[0];
  const float* key   = (const float*)d_in[1];
  const float* value = (const float*)d_in[2];
  float* S = (float*)d_out;
  float* T = S + (size_t)BATCH * LQ;

  char* ws = (char*)d_ws;
  const size_t arr = (size_t)BATCH * LP * KD * sizeof(float);  // 117,964,800 B
  float* kn = (float*)(ws);
  float* qn = (float*)(ws + arr);
  size_t off = 2 * arr;
  const size_t nc4 = (size_t)BATCH * LQ * NTILE * 4;   // 1,272,384 entries
  float* tV4 = (float*)(ws + off); off += nc4 * 4;
  unsigned short* tL4 = (unsigned short*)(ws + off); off += nc4 * 2;
  int* final_l = (int*)(ws + off); off += (size_t)BATCH * LQ * 4;
  int* flag_list = (int*)(ws + off); off += (size_t)BATCH * LQ * 4;
  off = (off + 255) & ~(size_t)255;
  int* flag_cnt = (int*)(ws + off);

  hipMemsetAsync(flag_cnt, 0, sizeof(int), stream);
  prep_np_kernel<<<dim3(LP, BATCH), 256, 0, stream>>>(key, kn, 0);
  prep_np_kernel<<<dim3(LP, BATCH), 256, 0, stream>>>(queue, qn, 1);
  // DIAGNOSTIC split: two half-batch brute dispatches (~325 us each) so any
  // hidden >~330 us dispatch surfaces in the top-5 profile by name.
  brute_mfma_kernel<<<dim3(LP / 128, LP / 128, BATCH / 2), 256, 0, stream>>>(
      kn, qn, tV4, tL4, 0);
  brute_mfma_kernel<<<dim3(LP / 128, LP / 128, BATCH / 2), 256, 0, stream>>>(
      kn, qn, tV4, tL4, BATCH / 2);
  finalize32_kernel<<<dim3((LQ + 255) / 256, 1, BATCH), 256, 0, stream>>>(
      tV4, tL4, S, final_l, flag_list, flag_cnt);
  refine_kernel<<<dim3(2048), 256, 0, stream>>>(
      flag_list, flag_cnt, kn, qn, tV4, tL4, S, final_l);
  gather_kernel<<<dim3((LQ + 255) / 256, 16, BATCH), 256, 0, stream>>>(
      final_l, value, T);
}

// Round 14
// 926.707 us; speedup vs baseline: 1.5265x; 1.3999x over previous
//
#include <hip/hip_runtime.h>
#include <math.h>

#define BATCH 8
#define CH 64
#define HW 96
#define HQ 47
#define LQ 2209         // 47*47
#define LP 2304         // padded to 18*128
#define KD 1600         // 64*25
#define NC9 576         // 64*9
#define NTILE 18        // LP/128 l-tiles
#define BK 32           // k-tile in brute (one MFMA K-step)
#define MARGIN 5e-5f    // screen near-tie window (worst-case err ~2.1e-5)
#define MAXCAND 2432    // 72 entries + 18*128 full-tile fallback

typedef __attribute__((ext_vector_type(8))) short short8;   // 8 bf16 (4 VGPR)
typedef __attribute__((ext_vector_type(4))) float f32x4;    // MFMA C/D frag

// ---------------------------------------------------------------------------
// numpy pairwise base case (n <= 128, n % 8 == 0 here): 8 accumulators,
// identical op sequence to numpy's pairwise_sum base branch.
// ---------------------------------------------------------------------------
__device__ float np_pairwise_base(const float* a, int n) {
#pragma clang fp contract(off)
  float r[8];
#pragma unroll
  for (int j = 0; j < 8; ++j) { float x = a[j]; r[j] = x * x; }
  const int nm8 = n - (n % 8);
  for (int i = 8; i < nm8; i += 8)
#pragma unroll
    for (int j = 0; j < 8; ++j) { float x = a[i + j]; r[j] = r[j] + x * x; }
  float res = ((r[0] + r[1]) + (r[2] + r[3])) + ((r[4] + r[5]) + (r[6] + r[7]));
  for (int i = nm8; i < n; ++i) { float x = a[i]; res = res + x * x; }
  return res;
}

// ---------------------------------------------------------------------------
// prep: unfold (k=5,p=1,s=2), L2-normalize with numpy-exact fp32 rounding.
// R13 profile showed the OLD thread-0 serial reduce was 393 us/dispatch
// (latency-bound scalar ds_read chain). Fix, preserving bit-exactness:
//  mode 0: numpy pairwise(1600) is a FIXED tree with 16 base segments
//    (96/104 per 200-chunk) -> compute bases on 16 parallel threads, then
//    combine partials in the exact tree order (15 fp32 adds, thread 0).
//  mode 1: strictly-sequential chain kept on thread 0, but float4 LDS
//    reads + unrolled squares let loads pipeline; adds stay in order.
// ---------------------------------------------------------------------------
__global__ __launch_bounds__(256) void prep_np_kernel(
    const float* __restrict__ src, float* __restrict__ out, int mode) {
  __shared__ __align__(16) float sRaw[KD];
  __shared__ float sPart[16];
  __shared__ float sDen;
  const int pos = blockIdx.x;
  const int b = blockIdx.y;
  const int t = threadIdx.x;
  const size_t obase = ((size_t)b * LP + pos) * KD;

  if (pos >= LQ) {
    for (int k = t; k < KD; k += 256) out[obase + k] = 0.f;
    return;
  }
  const int y0 = (pos / HQ) * 2 - 1, x0 = (pos % HQ) * 2 - 1;
  for (int k = t; k < KD; k += 256) {
    const int c = k / 25, r = k % 25, kh = r / 5, kw = r % 5;
    const int y = y0 + kh, x = x0 + kw;
    float v = 0.f;
    if (y >= 0 && y < HW && x >= 0 && x < HW)
      v = src[(((size_t)b * CH + c) * HW + y) * HW + x];
    sRaw[k] = v;
  }
  __syncthreads();
  if (mode == 0) {
    // 16 parallel base segments: chunk h=[h*200,(h+1)*200) splits (96,104)
    if (t < 16) {
      const int half = t >> 1, odd = t & 1;
      const int off = half * 200 + odd * 96;
      sPart[t] = np_pairwise_base(sRaw + off, odd ? 104 : 96);
    }
    __syncthreads();
    if (t == 0) {
#pragma clang fp contract(off)
      float s200[8];
#pragma unroll
      for (int i = 0; i < 8; ++i) s200[i] = sPart[2 * i] + sPart[2 * i + 1];
      float s400[4];
#pragma unroll
      for (int j = 0; j < 4; ++j) s400[j] = s200[2 * j] + s200[2 * j + 1];
      const float s800a = s400[0] + s400[1];
      const float s800b = s400[2] + s400[3];
      const float ss = s800a + s800b;
      const float nrm = (float)sqrt((double)ss);
      sDen = fmaxf(nrm, 1e-12f);
    }
  } else {
    if (t == 0) {
#pragma clang fp contract(off)
      float acc = 0.f;
      for (int k2 = 0; k2 < KD; k2 += 8) {
        const float4 a = *(const float4*)(sRaw + k2);
        const float4 b4 = *(const float4*)(sRaw + k2 + 4);
        acc = acc + a.x * a.x;
        acc = acc + a.y * a.y;
        acc = acc + a.z * a.z;
        acc = acc + a.w * a.w;
        acc = acc + b4.x * b4.x;
        acc = acc + b4.y * b4.y;
        acc = acc + b4.z * b4.z;
        acc = acc + b4.w * b4.w;
      }
      const float nrm = (float)sqrt((double)acc);
      sDen = fmaxf(nrm, 1e-12f);
    }
  }
  __syncthreads();
  const float den = sDen;
  for (int k = t; k < KD; k += 256) out[obase + k] = sRaw[k] / den;
}

// ---------------------------------------------------------------------------
// split staging via v_cvt_pk_bf16_f32: hi = cvt_pk(x0,x1);
// lo_i = x_i - bf2f(hi_i); lo = cvt_pk(lo0,lo1).  ~3 VALU/elem.
// ---------------------------------------------------------------------------
__device__ inline void stage8_pk(short* dh, short* dl, int soff,
                                 const float* __restrict__ src) {
  const float4 f0 = *(const float4*)src;
  const float4 f1 = *(const float4*)(src + 4);
  const float x[8] = {f0.x, f0.y, f0.z, f0.w, f1.x, f1.y, f1.z, f1.w};
  int hp[4], lp[4];
#pragma unroll
  for (int p = 0; p < 4; ++p) {
    int h;
    asm("v_cvt_pk_bf16_f32 %0, %1, %2" : "=v"(h) : "v"(x[2 * p]), "v"(x[2 * p + 1]));
    hp[p] = h;
    const float h0 = __uint_as_float(((unsigned)h) << 16);        // src0 -> low16
    const float h1 = __uint_as_float(((unsigned)h) & 0xFFFF0000u);
    const float l0 = x[2 * p] - h0;
    const float l1 = x[2 * p + 1] - h1;
    int l;
    asm("v_cvt_pk_bf16_f32 %0, %1, %2" : "=v"(l) : "v"(l0), "v"(l1));
    lp[p] = l;
  }
  *(int4*)(dh + soff) = *(int4*)hp;   // soff in shorts, 16B-aligned
  *(int4*)(dl + soff) = *(int4*)lp;
}

// compare-exchange: ensure (va,la) >= (vb,lb) in (value desc, index asc) order
__device__ inline void ce(float& va, int& la, float& vb, int& lb) {
  const bool sw = (vb > va) || (vb == va && lb < la);
  const float tv = sw ? vb : va; const float uv = sw ? va : vb;
  const int tl = sw ? lb : la;   const int ul = sw ? la : lb;
  va = tv; la = tl; vb = uv; lb = ul;
}

// merge two desc-sorted 4-lists (a = mine, y = theirs) -> top-4 in a.
// Batcher odd-even merge, pruned to the CEs that affect positions 0..3.
__device__ inline void merge4(float a[4], int al[4], float y[4], int yl[4]) {
  ce(a[0], al[0], y[0], yl[0]);
  ce(a[1], al[1], y[1], yl[1]);
  ce(a[2], al[2], y[2], yl[2]);
  ce(a[3], al[3], y[3], yl[3]);
  ce(a[2], al[2], y[0], yl[0]);
  ce(a[3], al[3], y[1], yl[1]);
  ce(a[1], al[1], a[2], al[2]);
  ce(a[3], al[3], y[0], yl[0]);
}

// ---------------------------------------------------------------------------
// brute_mfma: split-bf16 MFMA screen (hi*hi + hi*lo + lo*hi, fp32 acc).
// LDS layout [g][128][8] with row skew (row+2g)&127. Stores TOP-4 per
// (q, 128-l tile): in-lane top-4 -> shfl butterfly merge -> cross-wave
// merge via LDS -> global tV4/tL4 (u16 indices).
// ---------------------------------------------------------------------------
__global__ __launch_bounds__(256) void brute_mfma_kernel(
    const float* __restrict__ kn, const float* __restrict__ qn,
    float* __restrict__ tV4, unsigned short* __restrict__ tL4) {
  __shared__ __align__(16) short sKh[4 * 128 * 8];
  __shared__ __align__(16) short sKl[4 * 128 * 8];
  __shared__ __align__(16) short sQh[4 * 128 * 8];
  __shared__ __align__(16) short sQl[4 * 128 * 8];
  __shared__ float sWv[2][128][4];
  __shared__ unsigned short sWl[2][128][4];

  const int t = threadIdx.x;
  const int qt = blockIdx.x, lt = blockIdx.y, b = blockIdx.z;
  const int l0 = lt * 128, q0 = qt * 128;
  const int w = t >> 6, lane = t & 63;
  const int wl = w >> 1, wq = w & 1;
  const int cl = lane & 15, g = lane >> 4;

  f32x4 acc[4][4];
#pragma unroll
  for (int i = 0; i < 4; ++i)
#pragma unroll
    for (int j = 0; j < 4; ++j) {
      f32x4 z = {0.f, 0.f, 0.f, 0.f};
      acc[i][j] = z;
    }

  const int row0 = t >> 2, slot0 = t & 3;
  const int row1 = row0 + 64;
  const int soff0 = slot0 * 1024 + (((row0 + 2 * slot0) & 127) * 8); // shorts
  const int soff1 = slot0 * 1024 + (((row1 + 2 * slot0) & 127) * 8);
  const float* kp0 = kn + ((size_t)(b * LP + l0 + row0)) * KD + slot0 * 8;
  const float* kp1 = kn + ((size_t)(b * LP + l0 + row1)) * KD + slot0 * 8;
  const float* qp0 = qn + ((size_t)(b * LP + q0 + row0)) * KD + slot0 * 8;
  const float* qp1 = qn + ((size_t)(b * LP + q0 + row1)) * KD + slot0 * 8;

  for (int c0 = 0; c0 < KD; c0 += BK) {
    __syncthreads();  // previous iteration's frag reads done
    stage8_pk(sKh, sKl, soff0, kp0); stage8_pk(sKh, sKl, soff1, kp1);
    stage8_pk(sQh, sQl, soff0, qp0); stage8_pk(sQh, sQl, soff1, qp1);
    kp0 += BK; kp1 += BK; qp0 += BK; qp1 += BK;
    __syncthreads();
    short8 Ah[4], Al[4], Bh[4], Bl[4];
#pragma unroll
    for (int i = 0; i < 4; ++i) {
      const int ar = wl * 64 + i * 16 + cl;
      const int sa = g * 1024 + (((ar + 2 * g) & 127) * 8);
      Ah[i] = *(const short8*)(sKh + sa);
      Al[i] = *(const short8*)(sKl + sa);
      const int br = wq * 64 + i * 16 + cl;
      const int sb = g * 1024 + (((br + 2 * g) & 127) * 8);
      Bh[i] = *(const short8*)(sQh + sb);
      Bl[i] = *(const short8*)(sQl + sb);
    }
#pragma unroll
    for (int i = 0; i < 4; ++i)
#pragma unroll
      for (int j = 0; j < 4; ++j) {
        acc[i][j] = __builtin_amdgcn_mfma_f32_16x16x32_bf16(
            Al[i], Bh[j], acc[i][j], 0, 0, 0);
        acc[i][j] = __builtin_amdgcn_mfma_f32_16x16x32_bf16(
            Ah[i], Bl[j], acc[i][j], 0, 0, 0);
        acc[i][j] = __builtin_amdgcn_mfma_f32_16x16x32_bf16(
            Ah[i], Bh[j], acc[i][j], 0, 0, 0);
      }
  }

  // per-wave top-4 over its 64 l's, per q column
#pragma unroll
  for (int j = 0; j < 4; ++j) {
    float v[4] = {-1e30f, -1e30f, -1e30f, -1e30f};
    int li[4] = {0x7fffffff, 0x7fffffff, 0x7fffffff, 0x7fffffff};
#pragma unroll
    for (int i = 0; i < 4; ++i)
#pragma unroll
      for (int r = 0; r < 4; ++r) {
        const int ll = l0 + wl * 64 + i * 16 + g * 4 + r;   // ascending per lane
        const float nv = (ll < LQ) ? acc[i][j][r] : -1e30f;
        if (nv > v[3] || (nv == v[3] && ll < li[3])) {
          v[3] = nv; li[3] = ll;
          ce(v[2], li[2], v[3], li[3]);
          ce(v[1], li[1], v[2], li[2]);
          ce(v[0], li[0], v[1], li[1]);
        }
      }
#pragma unroll
    for (int mm = 0; mm < 2; ++mm) {
      const int m = mm ? 32 : 16;
      float y[4]; int yl[4];
#pragma unroll
      for (int e2 = 0; e2 < 4; ++e2) {
        y[e2] = __shfl_xor(v[e2], m, 64);
        yl[e2] = __shfl_xor(li[e2], m, 64);
      }
      merge4(v, li, y, yl);
    }
    if (lane < 16) {   // g == 0 quarter: all lanes hold identical merged list
      const int qq = wq * 64 + j * 16 + cl;
#pragma unroll
      for (int e2 = 0; e2 < 4; ++e2) {
        sWv[wl][qq][e2] = v[e2];
        sWl[wl][qq][e2] = (unsigned short)(li[e2] > 0xFFFF ? 0xFFFF : li[e2]);
      }
    }
  }
  __syncthreads();
  if (t < 128) {
    float v[4]; int li[4]; float y[4]; int yl[4];
#pragma unroll
    for (int e2 = 0; e2 < 4; ++e2) {
      v[e2] = sWv[0][t][e2]; li[e2] = sWl[0][t][e2];
      y[e2] = sWv[1][t][e2]; yl[e2] = sWl[1][t][e2];
    }
    merge4(v, li, y, yl);
    const int q = q0 + t;
    if (q < LQ) {
      const size_t o = ((size_t)(b * LQ + q) * NTILE + lt) * 4;
#pragma unroll
      for (int e2 = 0; e2 < 4; ++e2) {
        tV4[o + e2] = v[e2];
        tL4[o + e2] = (unsigned short)(li[e2] > 0xFFFF ? 0xFFFF : li[e2]);
      }
    }
  }
}

// ---------------------------------------------------------------------------
// finalize: scan 18 tiles x top-4 -> screen top-2 (value desc, index asc).
// Gap >= MARGIN guarantees screen argmax == reference fp32-rounded argmax;
// otherwise flag into a flat list for candidate-based exact refinement.
// ---------------------------------------------------------------------------
__global__ __launch_bounds__(256) void finalize32_kernel(
    const float* __restrict__ tV4, const unsigned short* __restrict__ tL4,
    float* __restrict__ S, int* __restrict__ final_l,
    int* __restrict__ flag_list, int* __restrict__ flag_cnt) {
  const int q = blockIdx.x * 256 + threadIdx.x;
  const int b = blockIdx.z;
  if (q >= LQ) return;
  const size_t cb = (size_t)(b * LQ + q) * NTILE * 4;
  float v1 = -1e30f, v2 = -1e30f;
  int l1 = 0x7fffffff, l2 = 0x7fffffff;
  for (int i = 0; i < NTILE * 4; ++i) {
    const float v = tV4[cb + i];
    const int l = tL4[cb + i];
    if (v > v1 || (v == v1 && l < l1)) { v2 = v1; l2 = l1; v1 = v; l1 = l; }
    else if (v > v2 || (v == v2 && l < l2)) { v2 = v; l2 = l; }
  }
  S[b * LQ + q] = v1;
  final_l[b * LQ + q] = l1;
  if (v1 - v2 < MARGIN) {
    const int slot = atomicAdd(flag_cnt, 1);
    if (slot < BATCH * LQ) flag_list[slot] = b * LQ + q;
  }
}

// ---------------------------------------------------------------------------
// refine: one block per flagged query (grid-stride). Candidates = stored
// tile entries with screen value >= v1 - MARGIN; if a tile's 4th entry
// clears the threshold the tile may hide more -> add its whole 128-l range
// (keeps the guarantee unconditional). Exact fp64 dot per candidate (one
// wave each), fp32-round, argmax with first-index tie rule.
// ---------------------------------------------------------------------------
__global__ __launch_bounds__(256) void refine_kernel(
    const int* __restrict__ flag_list, const int* __restrict__ flag_cnt,
    const float* __restrict__ kn, const float* __restrict__ qn,
    const float* __restrict__ tV4, const unsigned short* __restrict__ tL4,
    float* __restrict__ S, int* __restrict__ final_l) {
  __shared__ float sQrow[KD];
  __shared__ int sList[MAXCAND];
  __shared__ int sCnt;
  __shared__ float sBv[4];
  __shared__ int sBl[4];
  int n = *flag_cnt;
  if (n <= 0) return;
  if (n > BATCH * LQ) n = BATCH * LQ;
  const int t = threadIdx.x;
  const int wid = t >> 6, lane = t & 63;
  for (int e = blockIdx.x; e < n; e += gridDim.x) {
    __syncthreads();  // protect previous iteration's LDS reads
    const int bq = flag_list[e];
    const int b = bq / LQ, q = bq % LQ;
    if (t == 0) sCnt = 0;
    for (int k = t; k < KD; k += 256)
      sQrow[k] = qn[((size_t)(b * LP + q)) * KD + k];
    __syncthreads();
    const float thr = S[bq] - MARGIN;     // S holds screen v1 here
    const size_t cb = (size_t)(b * LQ + q) * NTILE * 4;
    if (t < NTILE * 4) {
      const float v = tV4[cb + t];
      if (v >= thr) {
        const int l = tL4[cb + t];
        if (l < LQ) { const int p = atomicAdd(&sCnt, 1); sList[p] = l; }
      }
    }
    if (t < NTILE) {
      const float v3 = tV4[cb + t * 4 + 3];   // tile's 4th-best
      if (v3 >= thr) {                         // tile may hide candidates
        const int lbase = t * 128;
        const int p = atomicAdd(&sCnt, 128);
        for (int m2 = 0; m2 < 128; ++m2) {
          const int ll = lbase + m2;
          sList[p + m2] = (ll < LQ) ? ll : 0;  // extra valid l's are harmless
        }
      }
    }
    __syncthreads();
    const int nc = sCnt;
    float bf = -1e30f; int bl = 0x7fffffff;
    for (int c = wid; c < nc; c += 4) {
      const int l = sList[c];
      const float* kr = kn + ((size_t)(b * LP + l)) * KD;
      double acc = 0.0;
#pragma unroll
      for (int k = 0; k < 25; ++k)
        acc = fma((double)kr[lane + 64 * k], (double)sQrow[lane + 64 * k], acc);
#pragma unroll
      for (int m2 = 1; m2 < 64; m2 <<= 1) acc += __shfl_xor(acc, m2, 64);
      const float f = (float)acc;              // fp32-rounded exact dot
      if (f > bf || (f == bf && l < bl)) { bf = f; bl = l; }
    }
    if (lane == 0) { sBv[wid] = bf; sBl[wid] = bl; }
    __syncthreads();
    if (t == 0) {
      float v1 = sBv[0]; int l1 = sBl[0];
#pragma unroll
      for (int wv = 1; wv < 4; ++wv)
        if (sBv[wv] > v1 || (sBv[wv] == v1 && sBl[wv] < l1)) {
          v1 = sBv[wv]; l1 = sBl[wv];
        }
      S[bq] = v1; final_l[bq] = l1;
    }
  }
}

// ---------------------------------------------------------------------------
// gather: value patches (k=3,p=1,s=1) at argmax positions.
// ---------------------------------------------------------------------------
__global__ __launch_bounds__(256) void gather_kernel(
    const int* __restrict__ final_l, const float* __restrict__ value,
    float* __restrict__ T) {
  const int q = blockIdx.x * 256 + threadIdx.x;
  const int g = blockIdx.y;
  const int b = blockIdx.z;
  if (q >= LQ) return;
  const int l = final_l[b * LQ + q];
  const int y0 = l / HW - 1;
  const int x0 = l % HW - 1;
#pragma unroll
  for (int cc = 0; cc < 36; ++cc) {
    const int c9 = g * 36 + cc;
    const int c = c9 / 9, r = c9 % 9;
    const int kh = r / 3, kw = r % 3;
    const int y = y0 + kh, x = x0 + kw;
    float v = 0.f;
    if (y >= 0 && y < HW && x >= 0 && x < HW)
      v = value[(((size_t)b * CH + c) * HW + y) * HW + x];
    T[((size_t)(b * NC9 + c9)) * LQ + q] = v;
  }
}

// ---------------------------------------------------------------------------
extern "C" void kernel_launch(void* const* d_in, const int* in_sizes, int n_in,
                              void* d_out, int out_size, void* d_ws,
                              size_t ws_size, hipStream_t stream) {
  const float* queue = (const float*)d_in[0];
  const float* key   = (const float*)d_in[1];
  const float* value = (const float*)d_in[2];
  float* S = (float*)d_out;
  float* T = S + (size_t)BATCH * LQ;

  char* ws = (char*)d_ws;
  const size_t arr = (size_t)BATCH * LP * KD * sizeof(float);  // 117,964,800 B
  float* kn = (float*)(ws);
  float* qn = (float*)(ws + arr);
  size_t off = 2 * arr;
  const size_t nc4 = (size_t)BATCH * LQ * NTILE * 4;   // 1,272,384 entries
  float* tV4 = (float*)(ws + off); off += nc4 * 4;
  unsigned short* tL4 = (unsigned short*)(ws + off); off += nc4 * 2;
  int* final_l = (int*)(ws + off); off += (size_t)BATCH * LQ * 4;
  int* flag_list = (int*)(ws + off); off += (size_t)BATCH * LQ * 4;
  off = (off + 255) & ~(size_t)255;
  int* flag_cnt = (int*)(ws + off);

  hipMemsetAsync(flag_cnt, 0, sizeof(int), stream);
  prep_np_kernel<<<dim3(LP, BATCH), 256, 0, stream>>>(key, kn, 0);
  prep_np_kernel<<<dim3(LP, BATCH), 256, 0, stream>>>(queue, qn, 1);
  brute_mfma_kernel<<<dim3(LP / 128, LP / 128, BATCH), 256, 0, stream>>>(
      kn, qn, tV4, tL4);
  finalize32_kernel<<<dim3((LQ + 255) / 256, 1, BATCH), 256, 0, stream>>>(
      tV4, tL4, S, final_l, flag_list, flag_cnt);
  refine_kernel<<<dim3(2048), 256, 0, stream>>>(
      flag_list, flag_cnt, kn, qn, tV4, tL4, S, final_l);
  gather_kernel<<<dim3((LQ + 255) / 256, 16, BATCH), 256, 0, stream>>>(
      final_l, value, T);
}